// Round 13
// baseline (144.532 us; speedup 1.0000x reference)
//
#include <hip/hip_runtime.h>
#include <math.h>

#define NTOK   16384
#define HDIM   1024
#define HHALF  512
#define NE     16
#define PI_F   3.14159265358979323846f

// d_out layout (concatenated reference outputs, all f32; indices stored as float)
#define OFF_TP  0
#define OFF_TI  (NTOK * 2)
#define OFF_DEC (NTOK * 4)
#define OFF_PH  (OFF_DEC + NTOK * NE)
#define OFF_PR  (OFF_PH + NTOK * NE)

typedef _Float16 half8 __attribute__((ext_vector_type(8)));
typedef _Float16 half4 __attribute__((ext_vector_type(4)));
typedef short    bf8   __attribute__((ext_vector_type(8)));
typedef short    bf4   __attribute__((ext_vector_type(4)));
typedef float f32x16 __attribute__((ext_vector_type(16)));
typedef float f32x4 __attribute__((ext_vector_type(4)));

#define SCALE      2048.0f
#define SCALE_INV  (1.0f / 2048.0f)
#define MFMA_F16(a,b,c)  __builtin_amdgcn_mfma_f32_32x32x16_f16(a,b,c,0,0,0)
#define MFMA_BF16(a,b,c) __builtin_amdgcn_mfma_f32_32x32x16_bf16(a,b,c,0,0,0)
#define MFMA16(a,b,c)    __builtin_amdgcn_mfma_f32_16x16x32_f16(a,b,c,0,0,0)

// lgkm-only barrier: LDS visibility; vmcnt stays counted (prefetches in flight).
#define BAR() asm volatile("s_waitcnt lgkmcnt(0)\n\ts_barrier" ::: "memory")

__device__ __forceinline__ float gelu_exact(float x) {
    return 0.5f * x * (1.0f + erff(x * 0.70710678118654752440f));
}
__device__ __forceinline__ short f32_to_bf16_bits(float f) {
    unsigned u = __builtin_bit_cast(unsigned, f);
    u += 0x7FFFu + ((u >> 16) & 1u);
    return (short)(u >> 16);
}

// ---------------------------------------------------------------------------
// Prologue: W image in ws (R11's proven layout) + zero the PH/PR raw-sum
// regions of d_out (gemm blocks atomicAdd partial GEMM2 sums into them).
// Image (short units): u = (((ph*32+kc)*8+sl)*8+f)*64+l, f = nf*4+kh*2+pl.
// col = sl*64+nf*32+(l&31); k = kc*32+kh*16+(l>>5)*8+j.
// pl=0: f16(W) bits; pl=1: bf16(W - f16(W)) bits (raw residual).
// ---------------------------------------------------------------------------
__global__ void __launch_bounds__(256)
qir_wtrans(const float* __restrict__ w1a, const float* __restrict__ w1p,
           short* __restrict__ wt, float* __restrict__ out)
{
    int u = blockIdx.x * 256 + threadIdx.x;   // 0..262143
    out[OFF_PH + u] = 0.0f;
    out[OFF_PH + 262144 + u] = 0.0f;

    int l  = u & 63;
    int f  = (u >> 6) & 7;
    int sl = (u >> 9) & 7;
    int kc = (u >> 12) & 31;
    int ph = u >> 17;
    int nf = f >> 2, kh = (f >> 1) & 1, pl = f & 1;
    int col = sl * 64 + nf * 32 + (l & 31);
    int k0  = kc * 32 + kh * 16 + (l >> 5) * 8;
    const float* __restrict__ W = ph ? w1p : w1a;
    bf8 v;
    #pragma unroll
    for (int j = 0; j < 8; ++j) {
        float x = W[(size_t)(k0 + j) * HHALF + col];
        _Float16 h = (_Float16)x;
        v[j] = pl ? f32_to_bf16_bits(x - (float)h)
                  : __builtin_bit_cast(short, h);
    }
    *(bf8*)&wt[(size_t)u * 8] = v;
}

// ---------------------------------------------------------------------------
// Main GEMM: block = 64 tokens x 128 cols x one phase; 4 waves, wave tile
// 64x32 with SINGLE scale-2048 accumulator (R11-verified 3-product split):
//   P1 f16(2048*xh, wh) + P2 f16(2048*xl, wh) + P3 bf16(2048*xh_b, wlo_b).
// acc = 32 regs/wave -> __launch_bounds__(256,3): 3 blocks/CU, 12 waves/CU
// in 3 independent barrier domains (the occupancy axis, untried until now).
// A staged in 2x12KB LDS (3 planes hi'/lo'/xb); B frags global->reg with
// prefetch across BAR; R8 kstep schedule otherwise verbatim.
// A buf layout: kh*6144 + oct*3072 + pl*1024 + row*16.
// LDS 32KB: A dbuf [0,24K); epilogue H [w*4K,16K), P [16K,32K).
// ---------------------------------------------------------------------------
__device__ __forceinline__ void kstep(
    int kc, const float* __restrict__ aptr, const short* __restrict__ bptr,
    char* Acur, char* Anxt, int a_rd, int a_w0,
    bf8 (&Bc)[4], bf8 (&Bn)[4],
    float4 (&xw)[2], float4 (&xl)[2],
    f32x16& acc0, f32x16& acc1)
{
    // issue next-next x and next B frags (stay in flight across BAR)
    if (kc + 2 < 32) {
        xl[0] = *(const float4*)(aptr + (kc + 2) * 32);
        xl[1] = *(const float4*)(aptr + (kc + 2) * 32 + 16);
    }
    if (kc + 1 < 32) {
        #pragma unroll
        for (int j = 0; j < 4; ++j)
            Bn[j] = *(const bf8*)(bptr + (size_t)(kc + 1) * 32768 + j * 512);
    }
    #pragma unroll
    for (int kh = 0; kh < 2; ++kh) {
        const char* Ah = Acur + kh * 6144 + a_rd;
        half8 xh0 = *(const half8*)(Ah);
        half8 xh1 = *(const half8*)(Ah + 512);
        half8 xl0 = *(const half8*)(Ah + 1024);
        half8 xl1 = *(const half8*)(Ah + 1536);
        bf8   xb0 = *(const bf8*)  (Ah + 2048);
        bf8   xb1 = *(const bf8*)  (Ah + 2560);
        half8 wh  = __builtin_bit_cast(half8, Bc[kh * 2]);
        bf8   wlo = Bc[kh * 2 + 1];
        acc0 = MFMA_F16(xh0, wh, acc0);
        acc1 = MFMA_F16(xh1, wh, acc1);
        acc0 = MFMA_F16(xl0, wh, acc0);
        acc1 = MFMA_F16(xl1, wh, acc1);
        acc0 = MFMA_BF16(xb0, wlo, acc0);
        acc1 = MFMA_BF16(xb1, wlo, acc1);
    }
    if (kc + 1 < 32) {
        #pragma unroll
        for (int kh = 0; kh < 2; ++kh) {
            float4 v = kh ? xw[1] : xw[0];
            _Float16 h0 = (_Float16)v.x, h1 = (_Float16)v.y,
                     h2 = (_Float16)v.z, h3 = (_Float16)v.w;
            const _Float16 S = (_Float16)SCALE;
            half4 hi = {(_Float16)(h0 * S), (_Float16)(h1 * S),
                        (_Float16)(h2 * S), (_Float16)(h3 * S)};
            half4 lo = {(_Float16)((v.x - (float)h0) * SCALE),
                        (_Float16)((v.y - (float)h1) * SCALE),
                        (_Float16)((v.z - (float)h2) * SCALE),
                        (_Float16)((v.w - (float)h3) * SCALE)};
            bf4 hb = {f32_to_bf16_bits((float)h0 * SCALE),
                      f32_to_bf16_bits((float)h1 * SCALE),
                      f32_to_bf16_bits((float)h2 * SCALE),
                      f32_to_bf16_bits((float)h3 * SCALE)};
            char* base = Anxt + kh * 6144 + a_w0;
            *(half4*)(base)        = hi;
            *(half4*)(base + 1024) = lo;
            *(bf4*)  (base + 2048) = hb;
        }
    }
    BAR();
}

__global__ void __launch_bounds__(256, 3)
qir_gemm(const float* __restrict__ xg, const short* __restrict__ wt,
         const float* __restrict__ b1a, const float* __restrict__ w2a, const float* __restrict__ b2a,
         const float* __restrict__ b1p, const float* __restrict__ w2p, const float* __restrict__ b2p,
         float* __restrict__ out)
{
    extern __shared__ char smem[];
    const int tid = threadIdx.x;
    const int l  = tid & 63;
    const int w  = tid >> 6;   // wave 0..3 owns cols nh*128 + w*32 .. +31
    // XCD-aligned decode: blocks sharing an x-panel (8 v-values) are
    // bid = m, m+256, ..., all == m (mod 8) -> same XCD L2. Consecutive
    // bids (same v) share the whole B panel -> co-resident L1/L2 hits.
    const int bid  = blockIdx.x;
    const int mblk = bid & 255;
    const int v    = bid >> 8;
    const int ph   = v & 1;
    const int nh   = v >> 1;          // 0..3
    const int tok0 = mblk * 64;

    const float* __restrict__ b1 = ph ? b1p : b1a;
    const float* __restrict__ w2 = ph ? w2p : w2a;
    const float* __restrict__ b2 = ph ? b2p : b2a;
    const short* __restrict__ wtp = wt + ((size_t)ph << 20);

    char* const Ab0 = smem;
    char* const Ab1 = smem + 12288;

    // A staging: thread -> (row r 0..63, k-quad kq 0..3); stages quads kq
    // (kh0) and kq+4 (kh1) each kstep.
    const int r  = tid >> 2;
    const int kq = tid & 3;
    const float* __restrict__ aptr = xg + (size_t)(tok0 + r) * HDIM + kq * 4;
    const int a_w0 = (kq >> 1) * 3072 + r * 16 + (kq & 1) * 8;
    // A frag read: kh*6144 + oct(l>>5)*3072 + pl*1024 + row*16 (rows mf*32+(l&31))
    const int a_rd = (l >> 5) * 3072 + (l & 31) * 16;

    // B frag pointer (short units): c32 = nh*4+w; sl=c32>>1, nf=c32&1.
    // frag(kc,kh,pl) at bptr + kc*32768 + (kh*2+pl)*512.
    const int c32 = nh * 4 + w;
    const short* __restrict__ bptr =
        wtp + ((size_t)(c32 >> 1) * 8 + (size_t)(c32 & 1) * 4) * 512 + (size_t)l * 8;

    f32x16 acc0{}, acc1{};
    #pragma unroll
    for (int rg = 0; rg < 16; ++rg) { acc0[rg] = 0.f; acc1[rg] = 0.f; }

    bf8 Bc[4], Bn[4];
    float4 xw[2], xl4[2];

    // prologue: stage A(0), preload B(0), prefetch x(1)
    {
        #pragma unroll
        for (int kh = 0; kh < 2; ++kh) {
            float4 vv = *(const float4*)(aptr + kh * 16);
            _Float16 h0 = (_Float16)vv.x, h1 = (_Float16)vv.y,
                     h2 = (_Float16)vv.z, h3 = (_Float16)vv.w;
            const _Float16 S = (_Float16)SCALE;
            half4 hi = {(_Float16)(h0 * S), (_Float16)(h1 * S),
                        (_Float16)(h2 * S), (_Float16)(h3 * S)};
            half4 lo = {(_Float16)((vv.x - (float)h0) * SCALE),
                        (_Float16)((vv.y - (float)h1) * SCALE),
                        (_Float16)((vv.z - (float)h2) * SCALE),
                        (_Float16)((vv.w - (float)h3) * SCALE)};
            bf4 hb = {f32_to_bf16_bits((float)h0 * SCALE),
                      f32_to_bf16_bits((float)h1 * SCALE),
                      f32_to_bf16_bits((float)h2 * SCALE),
                      f32_to_bf16_bits((float)h3 * SCALE)};
            char* base = Ab0 + kh * 6144 + a_w0;
            *(half4*)(base)        = hi;
            *(half4*)(base + 1024) = lo;
            *(bf4*)  (base + 2048) = hb;
        }
    }
    #pragma unroll
    for (int j = 0; j < 4; ++j) Bc[j] = *(const bf8*)(bptr + j * 512);
    xw[0] = *(const float4*)(aptr + 32);
    xw[1] = *(const float4*)(aptr + 48);
    BAR();

    for (int kk = 0; kk < 16; ++kk) {
        kstep(2 * kk,     aptr, bptr, Ab0, Ab1, a_rd, a_w0,
              Bc, Bn, xw, xl4, acc0, acc1);
        kstep(2 * kk + 1, aptr, bptr, Ab1, Ab0, a_rd, a_w0,
              Bn, Bc, xl4, xw, acc0, acc1);
    }

    // combine scale + bias + exact gelu (all rows of the wave share one col)
    const float bb = b1[nh * 128 + w * 32 + (l & 31)];
    #pragma unroll
    for (int rg = 0; rg < 16; ++rg) {
        acc0[rg] = gelu_exact(acc0[rg] * SCALE_INV + bb);
        acc1[rg] = gelu_exact(acc1[rg] * SCALE_INV + bb);
    }

    // ---- fused partial GEMM2: wave contracts its 32 h-cols (K=32) ----
    char* const Hw = smem + w * 4096;            // wave-private [4 oct][64 rows][16B]
    char* const hb = Hw + ((l >> 3) & 3) * 1024 + (l & 7) * 2;
    float* const P = (float*)(smem + 16384);     // [4 waves][64 tok][16 e]

    half8 w2h, w2l;
    #pragma unroll
    for (int j = 0; j < 8; ++j) {
        int kg = nh * 128 + w * 32 + (l >> 4) * 8 + j;
        float vv = w2[(size_t)kg * NE + (l & 15)];
        _Float16 hh = (_Float16)vv;
        w2h[j] = hh;
        w2l[j] = (_Float16)((vv - (float)hh) * SCALE);
    }

    f32x4 acc2[4], acc2s[4];
    #pragma unroll
    for (int m16 = 0; m16 < 4; ++m16)
        #pragma unroll
        for (int rg = 0; rg < 4; ++rg) { acc2[m16][rg] = 0.f; acc2s[m16][rg] = 0.f; }

    // hi pass
    #pragma unroll
    for (int rg = 0; rg < 16; ++rg) {
        int row0 = (rg & 3) + 8 * (rg >> 2) + 4 * (l >> 5);
        *(_Float16*)(hb + row0 * 16)        = (_Float16)acc0[rg];
        *(_Float16*)(hb + (32 + row0) * 16) = (_Float16)acc1[rg];
    }
    #pragma unroll
    for (int m16 = 0; m16 < 4; ++m16) {
        half8 a2 = *(const half8*)(Hw + (l >> 4) * 1024 +
                                   (m16 * 16 + (l & 15)) * 16);
        acc2[m16]  = MFMA16(a2, w2h, acc2[m16]);
        acc2s[m16] = MFMA16(a2, w2l, acc2s[m16]);
    }
    // lo pass
    #pragma unroll
    for (int rg = 0; rg < 16; ++rg) {
        int row0 = (rg & 3) + 8 * (rg >> 2) + 4 * (l >> 5);
        { float vv = acc0[rg]; _Float16 hh = (_Float16)vv;
          *(_Float16*)(hb + row0 * 16) = (_Float16)(vv - (float)hh); }
        { float vv = acc1[rg]; _Float16 hh = (_Float16)vv;
          *(_Float16*)(hb + (32 + row0) * 16) = (_Float16)(vv - (float)hh); }
    }
    #pragma unroll
    for (int m16 = 0; m16 < 4; ++m16) {
        half8 a2 = *(const half8*)(Hw + (l >> 4) * 1024 +
                                   (m16 * 16 + (l & 15)) * 16);
        acc2[m16] = MFMA16(a2, w2h, acc2[m16]);
    }

    #pragma unroll
    for (int m16 = 0; m16 < 4; ++m16)
        #pragma unroll
        for (int rg = 0; rg < 4; ++rg) {
            int row = m16 * 16 + ((l >> 4) << 2) + rg;
            P[w * 1024 + row * 16 + (l & 15)] =
                acc2[m16][rg] + acc2s[m16][rg] * SCALE_INV;
        }
    __syncthreads();

    #pragma unroll
    for (int rep = 0; rep < 4; ++rep) {
        int oi = tid + rep * 256;
        int t = oi >> 4, e = oi & 15;
        float sum = 0.25f * b2[e]
                  + P[0 * 1024 + t * 16 + e]
                  + P[1 * 1024 + t * 16 + e]
                  + P[2 * 1024 + t * 16 + e]
                  + P[3 * 1024 + t * 16 + e];
        atomicAdd(out + (ph ? OFF_PH : OFF_PR) + (size_t)(tok0 + t) * NE + e, sum);
    }
}

// ---------------------------------------------------------------------------
// Fallback (R1 kernel, raw-output variant) if ws too small for the image.
// ---------------------------------------------------------------------------
__global__ void __launch_bounds__(512)
qir_mlp(const float* __restrict__ xg,
        const float* __restrict__ w1a, const float* __restrict__ b1a,
        const float* __restrict__ w2a, const float* __restrict__ b2a,
        const float* __restrict__ w1p, const float* __restrict__ b1p,
        const float* __restrict__ w2p, const float* __restrict__ b2p,
        float* __restrict__ out)
{
    __shared__ float sh_w[16][HHALF];
    __shared__ float sh_x[16][68];

    const int tid  = threadIdx.x;
    const int cg   = tid & 63;
    const int tg   = tid >> 6;
    const int tok0 = blockIdx.x * 64;
    const int cA   = cg * 4;
    const int cB   = 256 + cg * 4;

    for (int phase = 0; phase < 2; ++phase) {
        const float* __restrict__ w1 = phase ? w1p : w1a;
        const float* __restrict__ b1 = phase ? b1p : b1a;
        const float* __restrict__ w2 = phase ? w2p : w2a;
        const float* __restrict__ b2 = phase ? b2p : b2a;

        float acc[8][8];
        #pragma unroll
        for (int t = 0; t < 8; ++t)
            #pragma unroll
            for (int c = 0; c < 8; ++c) acc[t][c] = 0.0f;

        float4 wreg[4];
        float4 xreg = make_float4(0.f, 0.f, 0.f, 0.f);

        auto load_chunk = [&](int kc) {
            #pragma unroll
            for (int p = 0; p < 4; ++p) {
                int f  = tid + p * 512;
                int k  = f >> 7;
                int c4 = (f & 127) << 2;
                wreg[p] = *(const float4*)&w1[(kc * 16 + k) * HHALF + c4];
            }
            if (tid < 256) {
                int t  = tid >> 2;
                int k4 = (tid & 3) << 2;
                xreg = *(const float4*)&xg[(size_t)(tok0 + t) * HDIM + kc * 16 + k4];
            }
        };

        load_chunk(0);
        for (int kc = 0; kc < HDIM / 16; ++kc) {
            __syncthreads();
            #pragma unroll
            for (int p = 0; p < 4; ++p) {
                int f  = tid + p * 512;
                int k  = f >> 7;
                int c4 = (f & 127) << 2;
                *(float4*)&sh_w[k][c4] = wreg[p];
            }
            if (tid < 256) {
                int t  = tid >> 2;
                int k4 = (tid & 3) << 2;
                sh_x[k4 + 0][t] = xreg.x;
                sh_x[k4 + 1][t] = xreg.y;
                sh_x[k4 + 2][t] = xreg.z;
                sh_x[k4 + 3][t] = xreg.w;
            }
            __syncthreads();
            if (kc + 1 < HDIM / 16) load_chunk(kc + 1);

            #pragma unroll 4
            for (int k = 0; k < 16; ++k) {
                float4 xa = *(const float4*)&sh_x[k][tg * 8];
                float4 xb = *(const float4*)&sh_x[k][tg * 8 + 4];
                float4 wa = *(const float4*)&sh_w[k][cA];
                float4 wb = *(const float4*)&sh_w[k][cB];
                float xs[8] = {xa.x, xa.y, xa.z, xa.w, xb.x, xb.y, xb.z, xb.w};
                float ws[8] = {wa.x, wa.y, wa.z, wa.w, wb.x, wb.y, wb.z, wb.w};
                #pragma unroll
                for (int t = 0; t < 8; ++t)
                    #pragma unroll
                    for (int c = 0; c < 8; ++c)
                        acc[t][c] = fmaf(xs[t], ws[c], acc[t][c]);
            }
        }

        {
            float4 bA4 = *(const float4*)&b1[cA];
            float4 bB4 = *(const float4*)&b1[cB];
            float bs[8] = {bA4.x, bA4.y, bA4.z, bA4.w, bB4.x, bB4.y, bB4.z, bB4.w};
            #pragma unroll
            for (int t = 0; t < 8; ++t)
                #pragma unroll
                for (int c = 0; c < 8; ++c)
                    acc[t][c] = gelu_exact(acc[t][c] + bs[c]);
        }

        for (int e = 0; e < NE; ++e) {
            float w2v[8];
            #pragma unroll
            for (int j = 0; j < 4; ++j) {
                w2v[j]     = w2[(cA + j) * NE + e];
                w2v[4 + j] = w2[(cB + j) * NE + e];
            }
            float bias2 = b2[e];
            #pragma unroll
            for (int t = 0; t < 8; ++t) {
                float s = 0.0f;
                #pragma unroll
                for (int j = 0; j < 8; ++j) s = fmaf(acc[t][j], w2v[j], s);
                #pragma unroll
                for (int off = 1; off < 64; off <<= 1)
                    s += __shfl_xor(s, off, 64);
                if (cg == 0) {
                    float raw   = s + bias2;
                    int   token = tok0 + tg * 8 + t;
                    out[(phase ? OFF_PH : OFF_PR) + (size_t)token * NE + e] = raw;
                }
            }
        }
    }
}

// ---------------------------------------------------------------------------
// Per-token epilogue: tanh on raw phases; softmax/rotations/probs/top-2.
// ---------------------------------------------------------------------------
__global__ void __launch_bounds__(256)
qir_epilogue(const float* __restrict__ ent, float* __restrict__ out)
{
    __shared__ float sh_c[120], sh_s[120];
    const int tid = threadIdx.x;
    if (tid < 120) {
        int rem = tid, i = 0;
        while (rem >= 15 - i) { rem -= 15 - i; ++i; }
        int j = i + 1 + rem;
        float ang = ent[i * NE + j] * 0.5f;
        sh_c[tid] = cosf(ang);
        sh_s[tid] = sinf(ang);
    }
    __syncthreads();

    const int token = blockIdx.x * 256 + tid;

    #pragma unroll
    for (int q = 0; q < 4; ++q) {
        float4 v = *(const float4*)&out[OFF_PH + (size_t)token * NE + q * 4];
        v.x = tanhf(v.x) * PI_F;
        v.y = tanhf(v.y) * PI_F;
        v.z = tanhf(v.z) * PI_F;
        v.w = tanhf(v.w) * PI_F;
        *(float4*)&out[OFF_PH + (size_t)token * NE + q * 4] = v;
    }

    float a[16];
    #pragma unroll
    for (int q = 0; q < 4; ++q) {
        float4 v = *(const float4*)&out[OFF_PR + (size_t)token * NE + q * 4];
        a[q*4+0] = v.x; a[q*4+1] = v.y; a[q*4+2] = v.z; a[q*4+3] = v.w;
    }

    float m = fabsf(a[0]);
    #pragma unroll
    for (int e = 1; e < 16; ++e) m = fmaxf(m, fabsf(a[e]));
    float ssum = 0.0f;
    #pragma unroll
    for (int e = 0; e < 16; ++e) { a[e] = expf(fabsf(a[e]) - m); ssum += a[e]; }
    float inv = 1.0f / ssum;
    #pragma unroll
    for (int e = 0; e < 16; ++e) a[e] = sqrtf(a[e] * inv);

    {
        int p = 0;
        #pragma unroll
        for (int i = 0; i < 16; ++i) {
            #pragma unroll
            for (int j = i + 1; j < 16; ++j) {
                float c = sh_c[p], s = sh_s[p]; ++p;
                float ai = a[i], aj = a[j];
                a[i] = c * ai - s * aj;
                a[j] = s * ai + c * aj;
            }
        }
    }

    #pragma unroll
    for (int q = 0; q < 4; ++q)
        *(float4*)&out[OFF_DEC + (size_t)token * NE + q * 4] =
            make_float4(a[q*4], a[q*4+1], a[q*4+2], a[q*4+3]);

    float pr[16];
    float s2 = 0.0f;
    #pragma unroll
    for (int e = 0; e < 16; ++e) { pr[e] = a[e] * a[e]; s2 += pr[e]; }
    float inv2 = 1.0f / fmaxf(s2, 1e-12f);
    #pragma unroll
    for (int e = 0; e < 16; ++e) pr[e] *= inv2;
    #pragma unroll
    for (int q = 0; q < 4; ++q)
        *(float4*)&out[OFF_PR + (size_t)token * NE + q * 4] =
            make_float4(pr[q*4], pr[q*4+1], pr[q*4+2], pr[q*4+3]);

    float bv = pr[0]; int bi = 0;
    #pragma unroll
    for (int e = 1; e < 16; ++e) if (pr[e] > bv) { bv = pr[e]; bi = e; }
    float sv = -1.0f; int si = 0;
    #pragma unroll
    for (int e = 0; e < 16; ++e) if (e != bi && pr[e] > sv) { sv = pr[e]; si = e; }
    float ts = fmaxf(fabsf(bv) + fabsf(sv), 1e-12f);
    out[OFF_TP + (size_t)token * 2 + 0] = bv / ts;
    out[OFF_TP + (size_t)token * 2 + 1] = sv / ts;
    out[OFF_TI + (size_t)token * 2 + 0] = (float)bi;
    out[OFF_TI + (size_t)token * 2 + 1] = (float)si;
}

extern "C" void kernel_launch(void* const* d_in, const int* in_sizes, int n_in,
                              void* d_out, int out_size, void* d_ws, size_t ws_size,
                              hipStream_t stream) {
    const float* xg  = (const float*)d_in[0];
    const float* w1a = (const float*)d_in[1];
    const float* b1a = (const float*)d_in[2];
    const float* w2a = (const float*)d_in[3];
    const float* b2a = (const float*)d_in[4];
    const float* w1p = (const float*)d_in[5];
    const float* b1p = (const float*)d_in[6];
    const float* w2p = (const float*)d_in[7];
    const float* b2p = (const float*)d_in[8];
    const float* ent = (const float*)d_in[9];
    float* out = (float*)d_out;

    if (ws_size >= (size_t)4 * 1024 * 1024) {
        short* wt = (short*)d_ws;
        qir_wtrans<<<1024, 256, 0, stream>>>(w1a, w1p, wt, out);
        qir_gemm<<<2048, 256, 32768, stream>>>(xg, wt, b1a, w2a, b2a,
                                               b1p, w2p, b2p, out);
    } else {
        qir_mlp<<<NTOK / 64, 512, 0, stream>>>(xg, w1a, b1a, w2a, b2a,
                                               w1p, b1p, w2p, b2p, out);
    }
    qir_epilogue<<<NTOK / 256, 256, 0, stream>>>(ent, out);
}

// Round 14
// 141.862 us; speedup vs baseline: 1.0188x; 1.0188x over previous
//
#include <hip/hip_runtime.h>
#include <math.h>

#define NTOK   16384
#define HDIM   1024
#define HHALF  512
#define NE     16
#define PI_F   3.14159265358979323846f

// d_out layout (concatenated reference outputs, all f32; indices stored as float)
#define OFF_TP  0
#define OFF_TI  (NTOK * 2)
#define OFF_DEC (NTOK * 4)
#define OFF_PH  (OFF_DEC + NTOK * NE)
#define OFF_PR  (OFF_PH + NTOK * NE)

typedef _Float16 half8 __attribute__((ext_vector_type(8)));
typedef _Float16 half4 __attribute__((ext_vector_type(4)));
typedef short    bf8   __attribute__((ext_vector_type(8)));
typedef short    bf4   __attribute__((ext_vector_type(4)));
typedef float f32x16 __attribute__((ext_vector_type(16)));
typedef float f32x4 __attribute__((ext_vector_type(4)));

#define SCALE      2048.0f
#define SCALE_INV  (1.0f / 2048.0f)
#define MFMA_F16(a,b,c)  __builtin_amdgcn_mfma_f32_32x32x16_f16(a,b,c,0,0,0)
#define MFMA_BF16(a,b,c) __builtin_amdgcn_mfma_f32_32x32x16_bf16(a,b,c,0,0,0)
#define MFMA16(a,b,c)    __builtin_amdgcn_mfma_f32_16x16x32_f16(a,b,c,0,0,0)

// lgkm-only barrier: LDS visibility; vmcnt stays counted (prefetches in flight).
#define BAR() asm volatile("s_waitcnt lgkmcnt(0)\n\ts_barrier" ::: "memory")

__device__ __forceinline__ float gelu_exact(float x) {
    return 0.5f * x * (1.0f + erff(x * 0.70710678118654752440f));
}
__device__ __forceinline__ short f32_to_bf16_bits(float f) {
    unsigned u = __builtin_bit_cast(unsigned, f);
    u += 0x7FFFu + ((u >> 16) & 1u);
    return (short)(u >> 16);
}

// ---------------------------------------------------------------------------
// Prologue: W image in ws (R11's proven layout) + zero the PH/PR raw-sum
// regions of d_out (gemm blocks atomicAdd partial GEMM2 sums into them).
// Image (short units): u = (((ph*32+kc)*8+sl)*8+f)*64+l, f = nf*4+kh*2+pl.
// col = sl*64+nf*32+(l&31); k = kc*32+kh*16+(l>>5)*8+j.
// pl=0: f16(W) bits; pl=1: bf16(W - f16(W)) bits (raw residual).
// ---------------------------------------------------------------------------
__global__ void __launch_bounds__(256)
qir_wtrans(const float* __restrict__ w1a, const float* __restrict__ w1p,
           short* __restrict__ wt, float* __restrict__ out)
{
    int u = blockIdx.x * 256 + threadIdx.x;   // 0..262143
    out[OFF_PH + u] = 0.0f;
    out[OFF_PH + 262144 + u] = 0.0f;

    int l  = u & 63;
    int f  = (u >> 6) & 7;
    int sl = (u >> 9) & 7;
    int kc = (u >> 12) & 31;
    int ph = u >> 17;
    int nf = f >> 2, kh = (f >> 1) & 1, pl = f & 1;
    int col = sl * 64 + nf * 32 + (l & 31);
    int k0  = kc * 32 + kh * 16 + (l >> 5) * 8;
    const float* __restrict__ W = ph ? w1p : w1a;
    bf8 v;
    #pragma unroll
    for (int j = 0; j < 8; ++j) {
        float x = W[(size_t)(k0 + j) * HHALF + col];
        _Float16 h = (_Float16)x;
        v[j] = pl ? f32_to_bf16_bits(x - (float)h)
                  : __builtin_bit_cast(short, h);
    }
    *(bf8*)&wt[(size_t)u * 8] = v;
}

// ---------------------------------------------------------------------------
// Main GEMM: block = 64 tokens x 128 cols x one phase; 4 waves, wave tile
// 64x32, SINGLE scale-2048 accumulator (3-product split, R11-verified):
//   P1 f16(2048*xh, wh) + P2 f16(2048*xl, wh) + P3 bf16(2048*xh_b, wlo_b).
// __launch_bounds__(256,3): 3 blocks/CU, 12 waves/CU, 3 barrier domains.
// NEW vs R13: (a) bid decode mblk=bid>>3, v=bid&7 -- consecutive 8 blocks
// share one x panel (single HBM fetch, L3 serves rest) and each v-group pins
// to one XCD so its 512KB B panel stays L2-resident; (b) R6-proven stride-80
// H layout in the epilogue (kills the 8-way scalar-write bank conflict).
// A buf layout: kh*6144 + oct*3072 + pl*1024 + row*16.
// LDS 36KB: A dbuf [0,24K); epilogue H [w*5120, 20K), P [20K,36K).
// ---------------------------------------------------------------------------
__device__ __forceinline__ void kstep(
    int kc, const float* __restrict__ aptr, const short* __restrict__ bptr,
    char* Acur, char* Anxt, int a_rd, int a_w0,
    bf8 (&Bc)[4], bf8 (&Bn)[4],
    float4 (&xw)[2], float4 (&xl)[2],
    f32x16& acc0, f32x16& acc1)
{
    // issue next-next x and next B frags (stay in flight across BAR)
    if (kc + 2 < 32) {
        xl[0] = *(const float4*)(aptr + (kc + 2) * 32);
        xl[1] = *(const float4*)(aptr + (kc + 2) * 32 + 16);
    }
    if (kc + 1 < 32) {
        #pragma unroll
        for (int j = 0; j < 4; ++j)
            Bn[j] = *(const bf8*)(bptr + (size_t)(kc + 1) * 32768 + j * 512);
    }
    #pragma unroll
    for (int kh = 0; kh < 2; ++kh) {
        const char* Ah = Acur + kh * 6144 + a_rd;
        half8 xh0 = *(const half8*)(Ah);
        half8 xh1 = *(const half8*)(Ah + 512);
        half8 xl0 = *(const half8*)(Ah + 1024);
        half8 xl1 = *(const half8*)(Ah + 1536);
        bf8   xb0 = *(const bf8*)  (Ah + 2048);
        bf8   xb1 = *(const bf8*)  (Ah + 2560);
        half8 wh  = __builtin_bit_cast(half8, Bc[kh * 2]);
        bf8   wlo = Bc[kh * 2 + 1];
        acc0 = MFMA_F16(xh0, wh, acc0);
        acc1 = MFMA_F16(xh1, wh, acc1);
        acc0 = MFMA_F16(xl0, wh, acc0);
        acc1 = MFMA_F16(xl1, wh, acc1);
        acc0 = MFMA_BF16(xb0, wlo, acc0);
        acc1 = MFMA_BF16(xb1, wlo, acc1);
    }
    if (kc + 1 < 32) {
        #pragma unroll
        for (int kh = 0; kh < 2; ++kh) {
            float4 v = kh ? xw[1] : xw[0];
            _Float16 h0 = (_Float16)v.x, h1 = (_Float16)v.y,
                     h2 = (_Float16)v.z, h3 = (_Float16)v.w;
            const _Float16 S = (_Float16)SCALE;
            half4 hi = {(_Float16)(h0 * S), (_Float16)(h1 * S),
                        (_Float16)(h2 * S), (_Float16)(h3 * S)};
            half4 lo = {(_Float16)((v.x - (float)h0) * SCALE),
                        (_Float16)((v.y - (float)h1) * SCALE),
                        (_Float16)((v.z - (float)h2) * SCALE),
                        (_Float16)((v.w - (float)h3) * SCALE)};
            bf4 hb = {f32_to_bf16_bits((float)h0 * SCALE),
                      f32_to_bf16_bits((float)h1 * SCALE),
                      f32_to_bf16_bits((float)h2 * SCALE),
                      f32_to_bf16_bits((float)h3 * SCALE)};
            char* base = Anxt + kh * 6144 + a_w0;
            *(half4*)(base)        = hi;
            *(half4*)(base + 1024) = lo;
            *(bf4*)  (base + 2048) = hb;
        }
    }
    BAR();
}

__global__ void __launch_bounds__(256, 3)
qir_gemm(const float* __restrict__ xg, const short* __restrict__ wt,
         const float* __restrict__ b1a, const float* __restrict__ w2a, const float* __restrict__ b2a,
         const float* __restrict__ b1p, const float* __restrict__ w2p, const float* __restrict__ b2p,
         float* __restrict__ out)
{
    extern __shared__ char smem[];
    const int tid = threadIdx.x;
    const int l  = tid & 63;
    const int w  = tid >> 6;   // wave 0..3 owns cols nh*128 + w*32 .. +31
    // Interleaved decode: consecutive 8 bids = same x panel (8 v-values,
    // dispatched together -> one HBM fetch + L3 hits). v == bid mod 8 pins
    // each v-group to one XCD (round-robin) -> its 512KB B panel L2-resident.
    const int bid  = blockIdx.x;
    const int mblk = bid >> 3;        // 0..255
    const int v    = bid & 7;
    const int ph   = v & 1;
    const int nh   = v >> 1;          // 0..3
    const int tok0 = mblk * 64;

    const float* __restrict__ b1 = ph ? b1p : b1a;
    const float* __restrict__ w2 = ph ? w2p : w2a;
    const float* __restrict__ b2 = ph ? b2p : b2a;
    const short* __restrict__ wtp = wt + ((size_t)ph << 20);

    char* const Ab0 = smem;
    char* const Ab1 = smem + 12288;

    // A staging: thread -> (row r 0..63, k-quad kq 0..3); stages quads kq
    // (kh0) and kq+4 (kh1) each kstep.
    const int r  = tid >> 2;
    const int kq = tid & 3;
    const float* __restrict__ aptr = xg + (size_t)(tok0 + r) * HDIM + kq * 4;
    const int a_w0 = (kq >> 1) * 3072 + r * 16 + (kq & 1) * 8;
    // A frag read: kh*6144 + oct(l>>5)*3072 + pl*1024 + row*16
    const int a_rd = (l >> 5) * 3072 + (l & 31) * 16;

    // B frag pointer (short units): c32 = nh*4+w; sl=c32>>1, nf=c32&1.
    // frag(kc,kh,pl) at bptr + kc*32768 + (kh*2+pl)*512.
    const int c32 = nh * 4 + w;
    const short* __restrict__ bptr =
        wtp + ((size_t)(c32 >> 1) * 8 + (size_t)(c32 & 1) * 4) * 512 + (size_t)l * 8;

    f32x16 acc0{}, acc1{};
    #pragma unroll
    for (int rg = 0; rg < 16; ++rg) { acc0[rg] = 0.f; acc1[rg] = 0.f; }

    bf8 Bc[4], Bn[4];
    float4 xw[2], xl4[2];

    // prologue: stage A(0), preload B(0), prefetch x(1)
    {
        #pragma unroll
        for (int kh = 0; kh < 2; ++kh) {
            float4 vv = *(const float4*)(aptr + kh * 16);
            _Float16 h0 = (_Float16)vv.x, h1 = (_Float16)vv.y,
                     h2 = (_Float16)vv.z, h3 = (_Float16)vv.w;
            const _Float16 S = (_Float16)SCALE;
            half4 hi = {(_Float16)(h0 * S), (_Float16)(h1 * S),
                        (_Float16)(h2 * S), (_Float16)(h3 * S)};
            half4 lo = {(_Float16)((vv.x - (float)h0) * SCALE),
                        (_Float16)((vv.y - (float)h1) * SCALE),
                        (_Float16)((vv.z - (float)h2) * SCALE),
                        (_Float16)((vv.w - (float)h3) * SCALE)};
            bf4 hb = {f32_to_bf16_bits((float)h0 * SCALE),
                      f32_to_bf16_bits((float)h1 * SCALE),
                      f32_to_bf16_bits((float)h2 * SCALE),
                      f32_to_bf16_bits((float)h3 * SCALE)};
            char* base = Ab0 + kh * 6144 + a_w0;
            *(half4*)(base)        = hi;
            *(half4*)(base + 1024) = lo;
            *(bf4*)  (base + 2048) = hb;
        }
    }
    #pragma unroll
    for (int j = 0; j < 4; ++j) Bc[j] = *(const bf8*)(bptr + j * 512);
    xw[0] = *(const float4*)(aptr + 32);
    xw[1] = *(const float4*)(aptr + 48);
    BAR();

    for (int kk = 0; kk < 16; ++kk) {
        kstep(2 * kk,     aptr, bptr, Ab0, Ab1, a_rd, a_w0,
              Bc, Bn, xw, xl4, acc0, acc1);
        kstep(2 * kk + 1, aptr, bptr, Ab1, Ab0, a_rd, a_w0,
              Bn, Bc, xl4, xw, acc0, acc1);
    }

    // combine scale + bias + exact gelu (all rows of the wave share one col)
    const float bb = b1[nh * 128 + w * 32 + (l & 31)];
    #pragma unroll
    for (int rg = 0; rg < 16; ++rg) {
        acc0[rg] = gelu_exact(acc0[rg] * SCALE_INV + bb);
        acc1[rg] = gelu_exact(acc1[rg] * SCALE_INV + bb);
    }

    // ---- fused partial GEMM2: wave contracts its 32 h-cols (K=32) ----
    // H: wave-private [64 rows][stride 80B] f16 tile (R6-proven, conflict-free)
    char* const Hw = smem + w * 5120;
    float* const P = (float*)(smem + 20480);     // [4 waves][64 tok][16 e]

    half8 w2h, w2l;
    #pragma unroll
    for (int j = 0; j < 8; ++j) {
        int kg = nh * 128 + w * 32 + (l >> 4) * 8 + j;
        float vv = w2[(size_t)kg * NE + (l & 15)];
        _Float16 hh = (_Float16)vv;
        w2h[j] = hh;
        w2l[j] = (_Float16)((vv - (float)hh) * SCALE);
    }

    f32x4 acc2[4], acc2s[4];
    #pragma unroll
    for (int m16 = 0; m16 < 4; ++m16)
        #pragma unroll
        for (int rg = 0; rg < 4; ++rg) { acc2[m16][rg] = 0.f; acc2s[m16][rg] = 0.f; }

    // hi pass
    #pragma unroll
    for (int rg = 0; rg < 16; ++rg) {
        int row0 = (rg & 3) + 8 * (rg >> 2) + 4 * (l >> 5);
        *(_Float16*)(Hw + row0 * 80 + (l & 31) * 2)        = (_Float16)acc0[rg];
        *(_Float16*)(Hw + (32 + row0) * 80 + (l & 31) * 2) = (_Float16)acc1[rg];
    }
    #pragma unroll
    for (int m16 = 0; m16 < 4; ++m16) {
        half8 a2 = *(const half8*)(Hw + (m16 * 16 + (l & 15)) * 80 + (l >> 4) * 16);
        acc2[m16]  = MFMA16(a2, w2h, acc2[m16]);
        acc2s[m16] = MFMA16(a2, w2l, acc2s[m16]);
    }
    // lo pass
    #pragma unroll
    for (int rg = 0; rg < 16; ++rg) {
        int row0 = (rg & 3) + 8 * (rg >> 2) + 4 * (l >> 5);
        { float vv = acc0[rg]; _Float16 hh = (_Float16)vv;
          *(_Float16*)(Hw + row0 * 80 + (l & 31) * 2) = (_Float16)(vv - (float)hh); }
        { float vv = acc1[rg]; _Float16 hh = (_Float16)vv;
          *(_Float16*)(Hw + (32 + row0) * 80 + (l & 31) * 2) = (_Float16)(vv - (float)hh); }
    }
    #pragma unroll
    for (int m16 = 0; m16 < 4; ++m16) {
        half8 a2 = *(const half8*)(Hw + (m16 * 16 + (l & 15)) * 80 + (l >> 4) * 16);
        acc2[m16] = MFMA16(a2, w2h, acc2[m16]);
    }

    #pragma unroll
    for (int m16 = 0; m16 < 4; ++m16)
        #pragma unroll
        for (int rg = 0; rg < 4; ++rg) {
            int row = m16 * 16 + ((l >> 4) << 2) + rg;
            P[w * 1024 + row * 16 + (l & 15)] =
                acc2[m16][rg] + acc2s[m16][rg] * SCALE_INV;
        }
    __syncthreads();

    #pragma unroll
    for (int rep = 0; rep < 4; ++rep) {
        int oi = tid + rep * 256;
        int t = oi >> 4, e = oi & 15;
        float sum = 0.25f * b2[e]
                  + P[0 * 1024 + t * 16 + e]
                  + P[1 * 1024 + t * 16 + e]
                  + P[2 * 1024 + t * 16 + e]
                  + P[3 * 1024 + t * 16 + e];
        atomicAdd(out + (ph ? OFF_PH : OFF_PR) + (size_t)(tok0 + t) * NE + e, sum);
    }
}

// ---------------------------------------------------------------------------
// Fallback (R1 kernel, raw-output variant) if ws too small for the image.
// ---------------------------------------------------------------------------
__global__ void __launch_bounds__(512)
qir_mlp(const float* __restrict__ xg,
        const float* __restrict__ w1a, const float* __restrict__ b1a,
        const float* __restrict__ w2a, const float* __restrict__ b2a,
        const float* __restrict__ w1p, const float* __restrict__ b1p,
        const float* __restrict__ w2p, const float* __restrict__ b2p,
        float* __restrict__ out)
{
    __shared__ float sh_w[16][HHALF];
    __shared__ float sh_x[16][68];

    const int tid  = threadIdx.x;
    const int cg   = tid & 63;
    const int tg   = tid >> 6;
    const int tok0 = blockIdx.x * 64;
    const int cA   = cg * 4;
    const int cB   = 256 + cg * 4;

    for (int phase = 0; phase < 2; ++phase) {
        const float* __restrict__ w1 = phase ? w1p : w1a;
        const float* __restrict__ b1 = phase ? b1p : b1a;
        const float* __restrict__ w2 = phase ? w2p : w2a;
        const float* __restrict__ b2 = phase ? b2p : b2a;

        float acc[8][8];
        #pragma unroll
        for (int t = 0; t < 8; ++t)
            #pragma unroll
            for (int c = 0; c < 8; ++c) acc[t][c] = 0.0f;

        float4 wreg[4];
        float4 xreg = make_float4(0.f, 0.f, 0.f, 0.f);

        auto load_chunk = [&](int kc) {
            #pragma unroll
            for (int p = 0; p < 4; ++p) {
                int f  = tid + p * 512;
                int k  = f >> 7;
                int c4 = (f & 127) << 2;
                wreg[p] = *(const float4*)&w1[(kc * 16 + k) * HHALF + c4];
            }
            if (tid < 256) {
                int t  = tid >> 2;
                int k4 = (tid & 3) << 2;
                xreg = *(const float4*)&xg[(size_t)(tok0 + t) * HDIM + kc * 16 + k4];
            }
        };

        load_chunk(0);
        for (int kc = 0; kc < HDIM / 16; ++kc) {
            __syncthreads();
            #pragma unroll
            for (int p = 0; p < 4; ++p) {
                int f  = tid + p * 512;
                int k  = f >> 7;
                int c4 = (f & 127) << 2;
                *(float4*)&sh_w[k][c4] = wreg[p];
            }
            if (tid < 256) {
                int t  = tid >> 2;
                int k4 = (tid & 3) << 2;
                sh_x[k4 + 0][t] = xreg.x;
                sh_x[k4 + 1][t] = xreg.y;
                sh_x[k4 + 2][t] = xreg.z;
                sh_x[k4 + 3][t] = xreg.w;
            }
            __syncthreads();
            if (kc + 1 < HDIM / 16) load_chunk(kc + 1);

            #pragma unroll 4
            for (int k = 0; k < 16; ++k) {
                float4 xa = *(const float4*)&sh_x[k][tg * 8];
                float4 xb = *(const float4*)&sh_x[k][tg * 8 + 4];
                float4 wa = *(const float4*)&sh_w[k][cA];
                float4 wb = *(const float4*)&sh_w[k][cB];
                float xs[8] = {xa.x, xa.y, xa.z, xa.w, xb.x, xb.y, xb.z, xb.w};
                float ws[8] = {wa.x, wa.y, wa.z, wa.w, wb.x, wb.y, wb.z, wb.w};
                #pragma unroll
                for (int t = 0; t < 8; ++t)
                    #pragma unroll
                    for (int c = 0; c < 8; ++c)
                        acc[t][c] = fmaf(xs[t], ws[c], acc[t][c]);
            }
        }

        {
            float4 bA4 = *(const float4*)&b1[cA];
            float4 bB4 = *(const float4*)&b1[cB];
            float bs[8] = {bA4.x, bA4.y, bA4.z, bA4.w, bB4.x, bB4.y, bB4.z, bB4.w};
            #pragma unroll
            for (int t = 0; t < 8; ++t)
                #pragma unroll
                for (int c = 0; c < 8; ++c)
                    acc[t][c] = gelu_exact(acc[t][c] + bs[c]);
        }

        for (int e = 0; e < NE; ++e) {
            float w2v[8];
            #pragma unroll
            for (int j = 0; j < 4; ++j) {
                w2v[j]     = w2[(cA + j) * NE + e];
                w2v[4 + j] = w2[(cB + j) * NE + e];
            }
            float bias2 = b2[e];
            #pragma unroll
            for (int t = 0; t < 8; ++t) {
                float s = 0.0f;
                #pragma unroll
                for (int j = 0; j < 8; ++j) s = fmaf(acc[t][j], w2v[j], s);
                #pragma unroll
                for (int off = 1; off < 64; off <<= 1)
                    s += __shfl_xor(s, off, 64);
                if (cg == 0) {
                    float raw   = s + bias2;
                    int   token = tok0 + tg * 8 + t;
                    out[(phase ? OFF_PH : OFF_PR) + (size_t)token * NE + e] = raw;
                }
            }
        }
    }
}

// ---------------------------------------------------------------------------
// Per-token epilogue: tanh on raw phases; softmax/rotations/probs/top-2.
// ---------------------------------------------------------------------------
__global__ void __launch_bounds__(256)
qir_epilogue(const float* __restrict__ ent, float* __restrict__ out)
{
    __shared__ float sh_c[120], sh_s[120];
    const int tid = threadIdx.x;
    if (tid < 120) {
        int rem = tid, i = 0;
        while (rem >= 15 - i) { rem -= 15 - i; ++i; }
        int j = i + 1 + rem;
        float ang = ent[i * NE + j] * 0.5f;
        sh_c[tid] = cosf(ang);
        sh_s[tid] = sinf(ang);
    }
    __syncthreads();

    const int token = blockIdx.x * 256 + tid;

    #pragma unroll
    for (int q = 0; q < 4; ++q) {
        float4 v = *(const float4*)&out[OFF_PH + (size_t)token * NE + q * 4];
        v.x = tanhf(v.x) * PI_F;
        v.y = tanhf(v.y) * PI_F;
        v.z = tanhf(v.z) * PI_F;
        v.w = tanhf(v.w) * PI_F;
        *(float4*)&out[OFF_PH + (size_t)token * NE + q * 4] = v;
    }

    float a[16];
    #pragma unroll
    for (int q = 0; q < 4; ++q) {
        float4 v = *(const float4*)&out[OFF_PR + (size_t)token * NE + q * 4];
        a[q*4+0] = v.x; a[q*4+1] = v.y; a[q*4+2] = v.z; a[q*4+3] = v.w;
    }

    float m = fabsf(a[0]);
    #pragma unroll
    for (int e = 1; e < 16; ++e) m = fmaxf(m, fabsf(a[e]));
    float ssum = 0.0f;
    #pragma unroll
    for (int e = 0; e < 16; ++e) { a[e] = expf(fabsf(a[e]) - m); ssum += a[e]; }
    float inv = 1.0f / ssum;
    #pragma unroll
    for (int e = 0; e < 16; ++e) a[e] = sqrtf(a[e] * inv);

    {
        int p = 0;
        #pragma unroll
        for (int i = 0; i < 16; ++i) {
            #pragma unroll
            for (int j = i + 1; j < 16; ++j) {
                float c = sh_c[p], s = sh_s[p]; ++p;
                float ai = a[i], aj = a[j];
                a[i] = c * ai - s * aj;
                a[j] = s * ai + c * aj;
            }
        }
    }

    #pragma unroll
    for (int q = 0; q < 4; ++q)
        *(float4*)&out[OFF_DEC + (size_t)token * NE + q * 4] =
            make_float4(a[q*4], a[q*4+1], a[q*4+2], a[q*4+3]);

    float pr[16];
    float s2 = 0.0f;
    #pragma unroll
    for (int e = 0; e < 16; ++e) { pr[e] = a[e] * a[e]; s2 += pr[e]; }
    float inv2 = 1.0f / fmaxf(s2, 1e-12f);
    #pragma unroll
    for (int e = 0; e < 16; ++e) pr[e] *= inv2;
    #pragma unroll
    for (int q = 0; q < 4; ++q)
        *(float4*)&out[OFF_PR + (size_t)token * NE + q * 4] =
            make_float4(pr[q*4], pr[q*4+1], pr[q*4+2], pr[q*4+3]);

    float bv = pr[0]; int bi = 0;
    #pragma unroll
    for (int e = 1; e < 16; ++e) if (pr[e] > bv) { bv = pr[e]; bi = e; }
    float sv = -1.0f; int si = 0;
    #pragma unroll
    for (int e = 0; e < 16; ++e) if (e != bi && pr[e] > sv) { sv = pr[e]; si = e; }
    float ts = fmaxf(fabsf(bv) + fabsf(sv), 1e-12f);
    out[OFF_TP + (size_t)token * 2 + 0] = bv / ts;
    out[OFF_TP + (size_t)token * 2 + 1] = sv / ts;
    out[OFF_TI + (size_t)token * 2 + 0] = (float)bi;
    out[OFF_TI + (size_t)token * 2 + 1] = (float)si;
}

extern "C" void kernel_launch(void* const* d_in, const int* in_sizes, int n_in,
                              void* d_out, int out_size, void* d_ws, size_t ws_size,
                              hipStream_t stream) {
    const float* xg  = (const float*)d_in[0];
    const float* w1a = (const float*)d_in[1];
    const float* b1a = (const float*)d_in[2];
    const float* w2a = (const float*)d_in[3];
    const float* b2a = (const float*)d_in[4];
    const float* w1p = (const float*)d_in[5];
    const float* b1p = (const float*)d_in[6];
    const float* w2p = (const float*)d_in[7];
    const float* b2p = (const float*)d_in[8];
    const float* ent = (const float*)d_in[9];
    float* out = (float*)d_out;

    if (ws_size >= (size_t)4 * 1024 * 1024) {
        short* wt = (short*)d_ws;
        qir_wtrans<<<1024, 256, 0, stream>>>(w1a, w1p, wt, out);
        qir_gemm<<<2048, 256, 36864, stream>>>(xg, wt, b1a, w2a, b2a,
                                               b1p, w2p, b2p, out);
    } else {
        qir_mlp<<<NTOK / 64, 512, 0, stream>>>(xg, w1a, b1a, w2a, b2a,
                                               w1p, b1p, w2p, b2p, out);
    }
    qir_epilogue<<<NTOK / 256, 256, 0, stream>>>(ent, out);
}